// Round 5
// baseline (298.180 us; speedup 1.0000x reference)
//
#include <hip/hip_runtime.h>
#include <stdint.h>

// ---------------------------------------------------------------------------
// Bucketed linear attention, round 4: GEMM switched to 32x32x16 MFMA
// (same LDS layout/swizzle/ledger as R3; half the MFMA issue slots, higher
// shape ceiling 2495 vs 2176 TF).
//   ws layout (<= 211 MB):
//     xb   bf16 x            33,554,432 B @ 0
//     wq   bf16 qkv_w         6,291,456 B @ 33554432
//     wp   bf16 proj_w        2,097,152 B @ 39845888
//     qkv  bf16 [16384][3072] 100,663,296 B @ 41943040   (reused as AT later)
//     Qf   bf16 [bkt][n][e]   33,554,432 B @ 142606336
//     ctxb bf16 [bkt][e][d]   33,554,432 B @ 176160768  (in-place excl scan)
//     ksum f32  [bkt][d]       1,048,576 B @ 209715200  (in-place excl scan)
// ---------------------------------------------------------------------------

typedef unsigned short u16;
typedef unsigned int u32;
typedef u16   u16x4  __attribute__((ext_vector_type(4)));
typedef u16   u16x8  __attribute__((ext_vector_type(8)));
typedef float f32x4  __attribute__((ext_vector_type(4)));
typedef float f32x16 __attribute__((ext_vector_type(16)));
typedef float float4v __attribute__((ext_vector_type(4)));
typedef __bf16 bf16x8 __attribute__((ext_vector_type(8)));

__device__ __forceinline__ u16 f2bf(float f) {
  return __builtin_bit_cast(u16, (__bf16)f);
}
__device__ __forceinline__ float bf2f(u16 h) {
  return (float)__builtin_bit_cast(__bf16, h);
}

__device__ __forceinline__ void stage16(const u16* g, u16* l) {
  __builtin_amdgcn_global_load_lds(
      (const __attribute__((address_space(1))) u32*)g,
      (__attribute__((address_space(3))) u32*)l, 16, 0, 0);
}

// --------------------------- fp32 -> bf16 convert ---------------------------
__global__ __launch_bounds__(256) void cvt_f32_to_bf16(
    const float* __restrict__ in, u16* __restrict__ out, int n4) {
  int i = blockIdx.x * 256 + threadIdx.x;
  if (i >= n4) return;
  float4v v = reinterpret_cast<const float4v*>(in)[i];
  u16x4 o;
  o.x = f2bf(v.x); o.y = f2bf(v.y); o.z = f2bf(v.z); o.w = f2bf(v.w);
  reinterpret_cast<u16x4*>(out)[i] = o;
}

// ------------------ 256x256 NT bf16 MFMA GEMM (32x32x16) --------------------
// C[M][N] = A[M][K] @ B[N][K]^T (+bias when fp32 out). BK=64, 8 waves (2Mx4N),
// wave output 128x64 = 4x2 frags of 32x32. LDS [2 dbuf][2 khalf][256][32] u16
// per operand (identical to R3). Swizzle: phys 16B slot = logical ^ ((row>>1)&3)
// on both global_load_lds SOURCE (LDS linear) and ds_read.
// 32x32x16 frag: lane reads 8 contiguous k at row (lane&31), logical slot
// ks*2 + (lane>>5); its required XOR is the SAME ((row>>1)&3) involution.
// Gates: vmcnt(4)+barrier per k-half (R3 ledger, unchanged).
template <bool BF16_OUT>
__global__ __launch_bounds__(512, 2) void gemm256(
    const u16* __restrict__ A,      // [M][K] bf16
    const u16* __restrict__ B,      // [N][K] bf16
    const float* __restrict__ bias, // [N] (when !BF16_OUT)
    void* __restrict__ Cv,
    int N, int K, int NT) {         // NT = K/64
  __shared__ u16 As[2][2][256][32];
  __shared__ u16 Bs[2][2][256][32];
  const int tid = threadIdx.x, lane = tid & 63, wave = tid >> 6;
  const int wm = wave >> 2, wn = wave & 3;
  const int l31 = lane & 31, lh = lane >> 5;
  const int ntn = N >> 8;
  const int cpx = gridDim.x >> 3;
  const int bid = (blockIdx.x & 7) * cpx + (blockIdx.x >> 3);
  const int bm = bid / ntn, bn = bid % ntn;

  // staging: thread covers 16B at row (j*128 + tid>>2), phys slot tid&3;
  // fetch logical slot (tid&3)^((tid>>3)&3) so LDS dest stays linear.
  const int srow = tid >> 2;
  const int gsl8 = ((tid & 3) ^ ((tid >> 3) & 3)) * 8;
  const u16* Ag = A + (size_t)(bm * 256 + srow) * K + gsl8;
  const u16* Bg = B + (size_t)(bn * 256 + srow) * K + gsl8;
  const size_t rj = (size_t)128 * K;

  // ds_read row-dependent XOR: ((row>>1)&3) with row = ... + l31.
  const int rxor = (l31 >> 1) & 3;

  f32x16 acc[4][2] = {};
  bf16x8 a0, a1, a2, a3, a4, a5, a6, a7, b0, b1, b2, b3;

#define STG(P, buf, kh, kt)                                        \
  { const u16* g_ = P##g + (kt) + (kh) * 32;                       \
    stage16(g_,      &P##s[buf][kh][wave * 16][0]);                \
    stage16(g_ + rj, &P##s[buf][kh][128 + wave * 16][0]); }

// A frag (32x32x16): row = wm*128 + mi*32 + l31, slot = (ks*2+lh)^rxor
#define LDA32(r_, kk, ks, mi)                                            \
  { r_ = *(const bf16x8*)(&As[cur][kk][wm * 128 + (mi) * 32 + l31][0] +  \
                          (((ks) * 2 + lh) ^ rxor) * 8); }
#define LDB32(r_, kk, ks, ni)                                            \
  { r_ = *(const bf16x8*)(&Bs[cur][kk][wn * 64 + (ni) * 32 + l31][0] +   \
                          (((ks) * 2 + lh) ^ rxor) * 8); }

#define MM32(x, y, z) z = __builtin_amdgcn_mfma_f32_32x32x16_bf16(x, y, z, 0, 0, 0)
#define MFMA8(x0, x1, x2, x3, y0, y1)                              \
  __builtin_amdgcn_s_setprio(1);                                   \
  MM32(x0, y0, acc[0][0]); MM32(x0, y1, acc[0][1]);                \
  MM32(x1, y0, acc[1][0]); MM32(x1, y1, acc[1][1]);                \
  MM32(x2, y0, acc[2][0]); MM32(x2, y1, acc[2][1]);                \
  MM32(x3, y0, acc[3][0]); MM32(x3, y1, acc[3][1]);                \
  __builtin_amdgcn_s_setprio(0);

#define BARF()                                                     \
  { asm volatile("" ::: "memory");                                 \
    __builtin_amdgcn_s_barrier();                                  \
    asm volatile("" ::: "memory"); }

  // prologue: stage tile 0 fully into buf 0, drain, barrier.
  STG(A, 0, 0, 0) STG(B, 0, 0, 0) STG(A, 0, 1, 0) STG(B, 0, 1, 0)
  asm volatile("s_waitcnt vmcnt(0)" ::: "memory");
  __builtin_amdgcn_s_barrier();
  asm volatile("" ::: "memory");

  for (int t = 0; t < NT; ++t) {
    const int cur = t & 1, nxt = cur ^ 1;
    const int ktn = (t + 1) << 6;
    const bool pre = (t + 1 < NT);
    // ---- k-half 0: 12 ds_reads up front; second MFMA8 pair stall-free ----
    LDB32(b0, 0, 0, 0) LDB32(b1, 0, 0, 1)
    LDA32(a0, 0, 0, 0) LDA32(a1, 0, 0, 1) LDA32(a2, 0, 0, 2) LDA32(a3, 0, 0, 3)
    LDB32(b2, 0, 1, 0) LDB32(b3, 0, 1, 1)
    LDA32(a4, 0, 1, 0) LDA32(a5, 0, 1, 1) LDA32(a6, 0, 1, 2) LDA32(a7, 0, 1, 3)
    if (pre) STG(A, nxt, 0, ktn)
    MFMA8(a0, a1, a2, a3, b0, b1)
    if (pre) STG(B, nxt, 0, ktn)
    MFMA8(a4, a5, a6, a7, b2, b3)
    // gate: all waves' k1 staging (prev iter) landed -> k1 readable
    if (pre) { asm volatile("s_waitcnt vmcnt(4)" ::: "memory"); }
    else     { asm volatile("s_waitcnt vmcnt(0)" ::: "memory"); }
    BARF()
    // ---- k-half 1 ----
    LDB32(b0, 1, 0, 0) LDB32(b1, 1, 0, 1)
    LDA32(a0, 1, 0, 0) LDA32(a1, 1, 0, 1) LDA32(a2, 1, 0, 2) LDA32(a3, 1, 0, 3)
    LDB32(b2, 1, 1, 0) LDB32(b3, 1, 1, 1)
    LDA32(a4, 1, 1, 0) LDA32(a5, 1, 1, 1) LDA32(a6, 1, 1, 2) LDA32(a7, 1, 1, 3)
    if (pre) STG(A, nxt, 1, ktn)
    MFMA8(a0, a1, a2, a3, b0, b1)
    if (pre) STG(B, nxt, 1, ktn)
    MFMA8(a4, a5, a6, a7, b2, b3)
    // gate: all waves' k0 staging (this iter) landed -> next tile k0 ok
    if (pre) { asm volatile("s_waitcnt vmcnt(4)" ::: "memory"); }
    BARF()
  }
#undef STG
#undef LDA32
#undef LDB32
#undef MM32
#undef MFMA8
#undef BARF

  // epilogue: 32x32 D layout (m74/m101): col = lane&31,
  // row = (reg&3) + 8*(reg>>2) + 4*(lane>>5)
  const int rbase = bm * 256 + wm * 128 + 4 * lh;
  const int cbase = bn * 256 + wn * 64 + l31;
  if constexpr (BF16_OUT) {
    u16* C = (u16*)Cv;
#pragma unroll
    for (int mi = 0; mi < 4; ++mi)
#pragma unroll
      for (int reg = 0; reg < 16; ++reg) {
        size_t r = (size_t)(rbase + mi * 32 + (reg & 3) + 8 * (reg >> 2)) * N;
#pragma unroll
        for (int ni = 0; ni < 2; ++ni)
          C[r + cbase + ni * 32] = f2bf(acc[mi][ni][reg]);
      }
  } else {
    float* C = (float*)Cv;
    float bv[2];
#pragma unroll
    for (int ni = 0; ni < 2; ++ni) bv[ni] = bias[cbase + ni * 32];
#pragma unroll
    for (int mi = 0; mi < 4; ++mi)
#pragma unroll
      for (int reg = 0; reg < 16; ++reg) {
        size_t r = (size_t)(rbase + mi * 32 + (reg & 3) + 8 * (reg >> 2)) * N;
#pragma unroll
        for (int ni = 0; ni < 2; ++ni)
          C[r + cbase + ni * 32] = acc[mi][ni][reg] + bv[ni];
      }
  }
}

// ------------------ feature maps + per-bucket K^T V (fused) -----------------
__global__ __launch_bounds__(256) void featuremap_ctx(
    const u16* __restrict__ qkv,  // [16384][3072] bf16
    u16* __restrict__ Q, u16* __restrict__ ctxb, float* __restrict__ ksum) {
  const int bid = blockIdx.x;
  const int u = bid & 63;
  const int bh = bid >> 6;
  const int b = bh >> 4, h = bh & 15;
  const int tid = threadIdx.x, lane = tid & 63, wave = tid >> 6;
  const int l15 = lane & 15, l4 = lane >> 4;
  __shared__ float ts[64][65];
  __shared__ u16 KtL[64][72];
  __shared__ u16 VtL[64][72];
  __shared__ float dp[64][4];

  const size_t mrow  = (size_t)b * 4096 + u * 64;
  const size_t obase = (size_t)bid * 4096;

  // Q: softmax over e (64 lanes = e), each wave 16 rows
#pragma unroll 1
  for (int r = 0; r < 16; ++r) {
    int n = wave * 16 + r;
    float v = bf2f(qkv[(mrow + n) * 3072 + h * 64 + lane]);
    float mx = v;
#pragma unroll
    for (int o = 32; o; o >>= 1) mx = fmaxf(mx, __shfl_xor(mx, o));
    float ex = __expf(v - mx);
    float sm = ex;
#pragma unroll
    for (int o = 32; o; o >>= 1) sm += __shfl_xor(sm, o);
    Q[obase + n * 64 + lane] = f2bf(ex / sm * 0.125f);
  }

  // K: exp + transpose into KtL
  {
    int n = tid >> 2, c = tid & 3;
    const u16* kp = qkv + (mrow + n) * 3072 + 1024 + h * 64 + c * 16;
#pragma unroll
    for (int j = 0; j < 16; ++j) ts[n][c * 16 + j] = __expf(bf2f(kp[j]));
  }
  __syncthreads();
  {
    int d = tid >> 2, c = tid & 3;
    u16x8 o0, o1;
#pragma unroll
    for (int j = 0; j < 8; ++j) o0[j] = f2bf(ts[c * 16 + j][d]);
#pragma unroll
    for (int j = 0; j < 8; ++j) o1[j] = f2bf(ts[c * 16 + 8 + j][d]);
    *reinterpret_cast<u16x8*>(&KtL[d][c * 16])     = o0;
    *reinterpret_cast<u16x8*>(&KtL[d][c * 16 + 8]) = o1;
  }
  __syncthreads();
  {
    int d = tid & 63, q = tid >> 6;
    float a = 0.f;
#pragma unroll
    for (int j = 0; j < 16; ++j) a += bf2f(KtL[d][q * 16 + j]);
    dp[d][q] = a;
  }
  {
    int n = tid >> 2, c = tid & 3;
    const u16* vp = qkv + (mrow + n) * 3072 + 2048 + h * 64 + c * 16;
#pragma unroll
    for (int j = 0; j < 16; ++j) ts[n][c * 16 + j] = bf2f(vp[j]);
  }
  __syncthreads();
  if (tid < 64)
    ksum[obase / 64 + tid] = dp[tid][0] + dp[tid][1] + dp[tid][2] + dp[tid][3];
  {
    int e = tid >> 2, c = tid & 3;
    u16x8 o0, o1;
#pragma unroll
    for (int j = 0; j < 8; ++j) o0[j] = f2bf(ts[c * 16 + j][e]);
#pragma unroll
    for (int j = 0; j < 8; ++j) o1[j] = f2bf(ts[c * 16 + 8 + j][e]);
    *reinterpret_cast<u16x8*>(&VtL[e][c * 16])     = o0;
    *reinterpret_cast<u16x8*>(&VtL[e][c * 16 + 8]) = o1;
  }
  __syncthreads();

  f32x4 acc[4] = {};
#pragma unroll
  for (int kk = 0; kk < 2; ++kk) {
    bf16x8 av = *reinterpret_cast<const bf16x8*>(&VtL[wave * 16 + l15][kk * 32 + l4 * 8]);
#pragma unroll
    for (int ni = 0; ni < 4; ++ni) {
      bf16x8 bk = *reinterpret_cast<const bf16x8*>(&KtL[ni * 16 + l15][kk * 32 + l4 * 8]);
      acc[ni] = __builtin_amdgcn_mfma_f32_16x16x32_bf16(av, bk, acc[ni], 0, 0, 0);
    }
  }
  u16* cb = ctxb + obase;
#pragma unroll
  for (int ni = 0; ni < 4; ++ni)
#pragma unroll
    for (int i = 0; i < 4; ++i)
      cb[(wave * 16 + l4 * 4 + i) * 64 + ni * 16 + l15] = f2bf(acc[ni][i]);
}

// -------------------- in-place exclusive cumsum over u ----------------------
__global__ __launch_bounds__(256) void scanctx(
    u16* __restrict__ ctxb, float* __restrict__ ksum) {
  const int bh = blockIdx.x >> 2, c = blockIdx.x & 3;
  const int tid = threadIdx.x;
  u16* p = ctxb + (size_t)bh * 64 * 4096 + c * 1024 + tid * 4;
  float* kp = ksum + (size_t)bh * 64 * 64 + tid;
  const bool dok = (c == 0) && (tid < 64);

  float r0 = 0.f, r1 = 0.f, r2 = 0.f, r3 = 0.f, runk = 0.f;
#define LC(i) (*reinterpret_cast<const u16x4*>(p + (size_t)(i) * 4096))
#define LK(i) (dok ? kp[(size_t)(i) * 64] : 0.f)
  u16x4 c0 = LC(0), c1 = LC(1), c2 = LC(2), c3 = LC(3);
  float k0 = LK(0), k1 = LK(1), k2 = LK(2), k3 = LK(3);
  for (int u = 0; u < 64; u += 4) {
    const int i4 = u + 4 < 64 ? u + 4 : 63, i5 = u + 5 < 64 ? u + 5 : 63;
    const int i6 = u + 6 < 64 ? u + 6 : 63, i7 = u + 7 < 64 ? u + 7 : 63;
    u16x4 n0 = LC(i4), n1 = LC(i5), n2 = LC(i6), n3 = LC(i7);
    float m0 = LK(i4), m1 = LK(i5), m2 = LK(i6), m3 = LK(i7);
#define STEP(idx, cv, kv)                                                  \
    {                                                                      \
      u16x4 o;                                                             \
      o.x = f2bf(r0); o.y = f2bf(r1); o.z = f2bf(r2); o.w = f2bf(r3);      \
      *reinterpret_cast<u16x4*>(p + (size_t)(idx) * 4096) = o;             \
      if (dok) kp[(size_t)(idx) * 64] = runk;                              \
      r0 += bf2f(cv.x); r1 += bf2f(cv.y); r2 += bf2f(cv.z);                \
      r3 += bf2f(cv.w); runk += kv;                                        \
    }
    STEP(u, c0, k0) STEP(u + 1, c1, k1) STEP(u + 2, c2, k2) STEP(u + 3, c3, k3)
#undef STEP
    c0 = n0; c1 = n1; c2 = n2; c3 = n3;
    k0 = m0; k1 = m1; k2 = m2; k3 = m3;
  }
#undef LC
#undef LK
}

// ---------------- apply: attn = (q @ ctx_excl) * Dinv -> AT -----------------
__global__ __launch_bounds__(256) void apply(
    const u16* __restrict__ Q, const u16* __restrict__ ctxc,
    const float* __restrict__ kcum, u16* __restrict__ AT) {
  const int bid = blockIdx.x;
  const int u = bid & 63, bh = bid >> 6, b = bh >> 4, h = bh & 15;
  const int tid = threadIdx.x, lane = tid & 63, wave = tid >> 6;
  const int l15 = lane & 15, l4 = lane >> 4;
  __shared__ float kc[64];
  __shared__ float dp[64][4];
  __shared__ float dinv[64];

  const size_t base = (size_t)bid * 4096;
  const u16* Qu = Q + base;
  if (tid < 64) kc[tid] = kcum[(size_t)bid * 64 + tid];
  __syncthreads();
  {
    int n = tid & 63, q = tid >> 6;
    const u16* qp = Qu + n * 64 + q * 16;
    float a = 0.f;
#pragma unroll
    for (int j = 0; j < 16; ++j) a += bf2f(qp[j]) * kc[q * 16 + j];
    dp[n][q] = a;
  }
  __syncthreads();
  if (tid < 64)
    dinv[tid] = 1.f / fmaxf(dp[tid][0] + dp[tid][1] + dp[tid][2] + dp[tid][3], 1e-3f);
  __syncthreads();

  f32x4 acc[4] = {};
  const u16* Cu = ctxc + base;
#pragma unroll
  for (int kk = 0; kk < 2; ++kk) {
    bf16x8 aq = *reinterpret_cast<const bf16x8*>(Qu + (wave * 16 + l15) * 64 + kk * 32 + l4 * 8);
#pragma unroll
    for (int ni = 0; ni < 4; ++ni) {
      bf16x8 bc = *reinterpret_cast<const bf16x8*>(Cu + (ni * 16 + l15) * 64 + kk * 32 + l4 * 8);
      acc[ni] = __builtin_amdgcn_mfma_f32_16x16x32_bf16(aq, bc, acc[ni], 0, 0, 0);
    }
  }
  const size_t orow = ((size_t)b * 4096 + u * 64 + wave * 16 + l4 * 4) * 1024 + h * 64;
#pragma unroll
  for (int i = 0; i < 4; ++i) {
    float di = dinv[wave * 16 + l4 * 4 + i];
#pragma unroll
    for (int ni = 0; ni < 4; ++ni)
      AT[orow + (size_t)i * 1024 + ni * 16 + l15] = f2bf(acc[ni][i] * di);
  }
}

// ----------------------------------------------------------------------------
extern "C" void kernel_launch(void* const* d_in, const int* in_sizes, int n_in,
                              void* d_out, int out_size, void* d_ws, size_t ws_size,
                              hipStream_t stream) {
  (void)in_sizes; (void)n_in; (void)out_size; (void)ws_size;
  const float* x      = (const float*)d_in[0];
  const float* qkv_w  = (const float*)d_in[1];
  const float* proj_w = (const float*)d_in[2];
  const float* proj_b = (const float*)d_in[3];
  float* out = (float*)d_out;

  char* ws = (char*)d_ws;
  u16* xb    = (u16*)(ws);
  u16* wq    = (u16*)(ws + 33554432);
  u16* wp    = (u16*)(ws + 39845888);
  u16* qkv   = (u16*)(ws + 41943040);
  u16* Qf    = (u16*)(ws + 142606336);
  u16* ctxb  = (u16*)(ws + 176160768);
  float* ksum = (float*)(ws + 209715200);
  u16* AT    = qkv;  // qkv region is dead after featuremap_ctx

  cvt_f32_to_bf16<<<dim3(16384), dim3(256), 0, stream>>>(x, xb, 16777216 / 4);
  cvt_f32_to_bf16<<<dim3(3072),  dim3(256), 0, stream>>>(qkv_w, wq, 3145728 / 4);
  cvt_f32_to_bf16<<<dim3(1024),  dim3(256), 0, stream>>>(proj_w, wp, 1048576 / 4);

  gemm256<true ><<<dim3(64 * 12), dim3(512), 0, stream>>>(xb, wq, nullptr, qkv,
                                                          3072, 1024, 16);
  featuremap_ctx<<<dim3(4096), dim3(256), 0, stream>>>(qkv, Qf, ctxb, ksum);
  scanctx<<<dim3(256), dim3(256), 0, stream>>>(ctxb, ksum);
  apply<<<dim3(4096), dim3(256), 0, stream>>>(Qf, ctxb, ksum, AT);
  gemm256<false><<<dim3(64 * 4), dim3(512), 0, stream>>>(AT, wp, proj_b, out,
                                                         1024, 1024, 16);
}

// Round 6
// 281.728 us; speedup vs baseline: 1.0584x; 1.0584x over previous
//
#include <hip/hip_runtime.h>
#include <stdint.h>

// ---------------------------------------------------------------------------
// Bucketed linear attention, round 5: back to 16x16x32 (conflict-free read
// pattern), K-loop re-scheduled: k1 ds_reads roll under k0 MFMAs, free
// mid-tile gate (vmcnt(0)+barrier on tile-old loads), counted end gate.
//   ws layout (<= 211 MB):
//     xb   bf16 x            33,554,432 B @ 0
//     wq   bf16 qkv_w         6,291,456 B @ 33554432
//     wp   bf16 proj_w        2,097,152 B @ 39845888
//     qkv  bf16 [16384][3072] 100,663,296 B @ 41943040   (reused as AT later)
//     Qf   bf16 [bkt][n][e]   33,554,432 B @ 142606336
//     ctxb bf16 [bkt][e][d]   33,554,432 B @ 176160768  (in-place excl scan)
//     ksum f32  [bkt][d]       1,048,576 B @ 209715200  (in-place excl scan)
// ---------------------------------------------------------------------------

typedef unsigned short u16;
typedef unsigned int u32;
typedef u16   u16x4  __attribute__((ext_vector_type(4)));
typedef u16   u16x8  __attribute__((ext_vector_type(8)));
typedef float f32x4  __attribute__((ext_vector_type(4)));
typedef float float4v __attribute__((ext_vector_type(4)));
typedef __bf16 bf16x8 __attribute__((ext_vector_type(8)));

__device__ __forceinline__ u16 f2bf(float f) {
  return __builtin_bit_cast(u16, (__bf16)f);
}
__device__ __forceinline__ float bf2f(u16 h) {
  return (float)__builtin_bit_cast(__bf16, h);
}

__device__ __forceinline__ void stage16(const u16* g, u16* l) {
  __builtin_amdgcn_global_load_lds(
      (const __attribute__((address_space(1))) u32*)g,
      (__attribute__((address_space(3))) u32*)l, 16, 0, 0);
}

// ------------------- fp32 -> bf16 convert (all 3 inputs) --------------------
// ranges (u16x4 units): x 4194304 | qkv_w 786432 | proj_w 262144
__global__ __launch_bounds__(256) void cvt_all(
    const float* __restrict__ x, const float* __restrict__ wqf,
    const float* __restrict__ wpf, u16* __restrict__ xb,
    u16* __restrict__ wq, u16* __restrict__ wp) {
  int i = blockIdx.x * 256 + threadIdx.x;
  const float* in; u16* out; int j;
  if (i < 4194304)      { in = x;   out = xb; j = i; }
  else if (i < 4980736) { in = wqf; out = wq; j = i - 4194304; }
  else                  { in = wpf; out = wp; j = i - 4980736; }
  float4v v = reinterpret_cast<const float4v*>(in)[j];
  u16x4 o;
  o.x = f2bf(v.x); o.y = f2bf(v.y); o.z = f2bf(v.z); o.w = f2bf(v.w);
  reinterpret_cast<u16x4*>(out)[j] = o;
}

// ------------------ 256x256 NT bf16 MFMA GEMM (rolled K-loop) ---------------
// C[M][N] = A[M][K] @ B[N][K]^T (+bias when fp32 out). BK=64, 8 waves (2Mx4N),
// wave output 128x64, 16x16x32 MFMA. LDS [2 dbuf][2 khalf][256][32] u16.
// Swizzle: phys 16B slot = logical ^ ((row>>1)&3) on global SOURCE of
// global_load_lds (LDS dest linear) and on ds_read (R3 pattern, 0 conflicts).
// Tile schedule:
//   [entry: k0 ready] 12 ds_reads (k0) ; vmcnt(0) [tile-old k1 stages, free]
//   barrier  -> all waves' k1 landed
//   STG x4 (t+1 full tile, 8 loads)
//   4x MFMA8(k0) with k1's 12 ds_reads rolled between groups
//   4x MFMA8(k1)  (operands pre-loaded, no wait)
//   vmcnt(4) [k0(t+1) landed, k1(t+1) in flight] ; barrier
template <bool BF16_OUT>
__global__ __launch_bounds__(512, 2) void gemm256(
    const u16* __restrict__ A,      // [M][K] bf16
    const u16* __restrict__ B,      // [N][K] bf16
    const float* __restrict__ bias, // [N] (when !BF16_OUT)
    void* __restrict__ Cv,
    int N, int K, int NT) {         // NT = K/64
  __shared__ u16 As[2][2][256][32];
  __shared__ u16 Bs[2][2][256][32];
  const int tid = threadIdx.x, lane = tid & 63, wave = tid >> 6;
  const int wm = wave >> 2, wn = wave & 3;
  const int l15 = lane & 15, l4 = lane >> 4;
  const int ntn = N >> 8;
  const int cpx = gridDim.x >> 3;
  const int bid = (blockIdx.x & 7) * cpx + (blockIdx.x >> 3);
  const int bm = bid / ntn, bn = bid % ntn;

  // staging: thread covers 16B at row (j*128 + tid>>2), phys slot tid&3;
  // fetch logical slot (tid&3)^((tid>>3)&3) so LDS dest stays linear.
  const int srow = tid >> 2;
  const int gsl8 = ((tid & 3) ^ ((tid >> 3) & 3)) * 8;
  const u16* Ag = A + (size_t)(bm * 256 + srow) * K + gsl8;
  const u16* Bg = B + (size_t)(bn * 256 + srow) * K + gsl8;
  const size_t rj = (size_t)128 * K;

  // ds_read: physical slot = l4 ^ ((row>>1)&3); row = base16 + l15.
  const int slotr = (l4 ^ ((l15 >> 1) & 3)) * 8;

  f32x4 acc[8][4] = {};

#define STG(P, buf, kh, kt)                                        \
  { const u16* g_ = P##g + (kt) + (kh) * 32;                       \
    stage16(g_,      &P##s[buf][kh][wave * 16][0]);                \
    stage16(g_ + rj, &P##s[buf][kh][128 + wave * 16][0]); }

#define LDA1(r_, kk, mh, fi)                                                  \
  { r_ = *(const bf16x8*)(&As[cur][kk][wm * 128 + (mh) * 64 + (fi) * 16 + l15][0] + slotr); }
#define LDB1(r_, kk, ni)                                                      \
  { r_ = *(const bf16x8*)(&Bs[cur][kk][wn * 64 + (ni) * 16 + l15][0] + slotr); }

#define MM(x, y, z) z = __builtin_amdgcn_mfma_f32_16x16x32_bf16(x, y, z, 0, 0, 0)
#define M8(x0, x1, y0, y1, y2, y3, i0, i1)                         \
  __builtin_amdgcn_s_setprio(1);                                   \
  MM(x0, y0, acc[i0][0]); MM(x0, y1, acc[i0][1]);                  \
  MM(x0, y2, acc[i0][2]); MM(x0, y3, acc[i0][3]);                  \
  MM(x1, y0, acc[i1][0]); MM(x1, y1, acc[i1][1]);                  \
  MM(x1, y2, acc[i1][2]); MM(x1, y3, acc[i1][3]);                  \
  __builtin_amdgcn_s_setprio(0);

  // prologue: stage tile 0 fully into buf 0; k0 landed, k1 left in flight.
  STG(A, 0, 0, 0) STG(B, 0, 0, 0) STG(A, 0, 1, 0) STG(B, 0, 1, 0)
  asm volatile("s_waitcnt vmcnt(4)" ::: "memory");
  __builtin_amdgcn_s_barrier();
  asm volatile("" ::: "memory");

  for (int t = 0; t < NT; ++t) {
    const int cur = t & 1, nxt = cur ^ 1;
    const int ktn = (t + 1) << 6;
    const bool pre = (t + 1 < NT);
    bf16x8 bk0, bk1, bk2, bk3, p0, p1, p2, p3, q0, q1, q2, q3;
    bf16x8 ck0, ck1, ck2, ck3, r0, r1, r2, r3, s0, s1, s2, s3;
    // entry reads: k-half 0 (guaranteed by previous tile's end gate)
    LDB1(bk0, 0, 0) LDB1(bk1, 0, 1) LDB1(bk2, 0, 2) LDB1(bk3, 0, 3)
    LDA1(p0, 0, 0, 0) LDA1(p1, 0, 0, 1) LDA1(p2, 0, 0, 2) LDA1(p3, 0, 0, 3)
    LDA1(q0, 0, 1, 0) LDA1(q1, 0, 1, 1) LDA1(q2, 0, 1, 2) LDA1(q3, 0, 1, 3)
    // free gate: own k1-stage loads (issued a full tile ago) drained;
    // barrier promotes to all-waves -> k1 readable below.
    asm volatile("s_waitcnt vmcnt(0)" ::: "memory");
    __builtin_amdgcn_s_barrier();
    asm volatile("" ::: "memory");
    if (pre) {
      STG(A, nxt, 0, ktn) STG(B, nxt, 0, ktn)
      STG(A, nxt, 1, ktn) STG(B, nxt, 1, ktn)
    }
    // k0 MFMAs with k1 reads rolled in (execute during MFMA issue windows)
    M8(p0, p1, bk0, bk1, bk2, bk3, 0, 1)
    LDA1(r0, 1, 0, 0) LDA1(r1, 1, 0, 1)
    M8(p2, p3, bk0, bk1, bk2, bk3, 2, 3)
    LDA1(r2, 1, 0, 2) LDA1(r3, 1, 0, 3)
    M8(q0, q1, bk0, bk1, bk2, bk3, 4, 5)
    LDA1(s0, 1, 1, 0) LDA1(s1, 1, 1, 1)
    M8(q2, q3, bk0, bk1, bk2, bk3, 6, 7)
    LDA1(s2, 1, 1, 2) LDA1(s3, 1, 1, 3)
    LDB1(ck0, 1, 0) LDB1(ck1, 1, 1) LDB1(ck2, 1, 2) LDB1(ck3, 1, 3)
    // k1 MFMAs: operands already resident
    M8(r0, r1, ck0, ck1, ck2, ck3, 0, 1)
    M8(r2, r3, ck0, ck1, ck2, ck3, 2, 3)
    M8(s0, s1, ck0, ck1, ck2, ck3, 4, 5)
    M8(s2, s3, ck0, ck1, ck2, ck3, 6, 7)
    // end gate: k0(t+1) landed (counted), k1(t+1) stays in flight
    if (pre) { asm volatile("s_waitcnt vmcnt(4)" ::: "memory"); }
    asm volatile("" ::: "memory");
    __builtin_amdgcn_s_barrier();
    asm volatile("" ::: "memory");
  }
#undef STG
#undef LDA1
#undef LDB1
#undef MM
#undef M8

  // epilogue: D row=(lane>>4)*4+reg, col=lane&15
  const int row0 = bm * 256 + wm * 128 + l4 * 4;
  const int col0 = bn * 256 + wn * 64 + l15;
  if constexpr (BF16_OUT) {
    u16* C = (u16*)Cv;
#pragma unroll
    for (int mi = 0; mi < 8; ++mi)
#pragma unroll
      for (int i = 0; i < 4; ++i) {
        size_t r = (size_t)(row0 + mi * 16 + i) * N;
#pragma unroll
        for (int ni = 0; ni < 4; ++ni)
          C[r + col0 + ni * 16] = f2bf(acc[mi][ni][i]);
      }
  } else {
    float* C = (float*)Cv;
    float bv[4];
#pragma unroll
    for (int ni = 0; ni < 4; ++ni) bv[ni] = bias[col0 + ni * 16];
#pragma unroll
    for (int mi = 0; mi < 8; ++mi)
#pragma unroll
      for (int i = 0; i < 4; ++i) {
        size_t r = (size_t)(row0 + mi * 16 + i) * N;
#pragma unroll
        for (int ni = 0; ni < 4; ++ni)
          C[r + col0 + ni * 16] = acc[mi][ni][i] + bv[ni];
      }
  }
}

// ------------------ feature maps + per-bucket K^T V (fused) -----------------
__global__ __launch_bounds__(256) void featuremap_ctx(
    const u16* __restrict__ qkv,  // [16384][3072] bf16
    u16* __restrict__ Q, u16* __restrict__ ctxb, float* __restrict__ ksum) {
  const int bid = blockIdx.x;
  const int u = bid & 63;
  const int bh = bid >> 6;
  const int b = bh >> 4, h = bh & 15;
  const int tid = threadIdx.x, lane = tid & 63, wave = tid >> 6;
  const int l15 = lane & 15, l4 = lane >> 4;
  __shared__ float ts[64][65];
  __shared__ u16 KtL[64][72];
  __shared__ u16 VtL[64][72];
  __shared__ float dp[64][4];

  const size_t mrow  = (size_t)b * 4096 + u * 64;
  const size_t obase = (size_t)bid * 4096;

  // Q: softmax over e (64 lanes = e), each wave 16 rows
#pragma unroll 1
  for (int r = 0; r < 16; ++r) {
    int n = wave * 16 + r;
    float v = bf2f(qkv[(mrow + n) * 3072 + h * 64 + lane]);
    float mx = v;
#pragma unroll
    for (int o = 32; o; o >>= 1) mx = fmaxf(mx, __shfl_xor(mx, o));
    float ex = __expf(v - mx);
    float sm = ex;
#pragma unroll
    for (int o = 32; o; o >>= 1) sm += __shfl_xor(sm, o);
    Q[obase + n * 64 + lane] = f2bf(ex / sm * 0.125f);
  }

  // K: exp + transpose into KtL
  {
    int n = tid >> 2, c = tid & 3;
    const u16* kp = qkv + (mrow + n) * 3072 + 1024 + h * 64 + c * 16;
#pragma unroll
    for (int j = 0; j < 16; ++j) ts[n][c * 16 + j] = __expf(bf2f(kp[j]));
  }
  __syncthreads();
  {
    int d = tid >> 2, c = tid & 3;
    u16x8 o0, o1;
#pragma unroll
    for (int j = 0; j < 8; ++j) o0[j] = f2bf(ts[c * 16 + j][d]);
#pragma unroll
    for (int j = 0; j < 8; ++j) o1[j] = f2bf(ts[c * 16 + 8 + j][d]);
    *reinterpret_cast<u16x8*>(&KtL[d][c * 16])     = o0;
    *reinterpret_cast<u16x8*>(&KtL[d][c * 16 + 8]) = o1;
  }
  __syncthreads();
  {
    int d = tid & 63, q = tid >> 6;
    float a = 0.f;
#pragma unroll
    for (int j = 0; j < 16; ++j) a += bf2f(KtL[d][q * 16 + j]);
    dp[d][q] = a;
  }
  {
    int n = tid >> 2, c = tid & 3;
    const u16* vp = qkv + (mrow + n) * 3072 + 2048 + h * 64 + c * 16;
#pragma unroll
    for (int j = 0; j < 16; ++j) ts[n][c * 16 + j] = bf2f(vp[j]);
  }
  __syncthreads();
  if (tid < 64)
    ksum[obase / 64 + tid] = dp[tid][0] + dp[tid][1] + dp[tid][2] + dp[tid][3];
  {
    int e = tid >> 2, c = tid & 3;
    u16x8 o0, o1;
#pragma unroll
    for (int j = 0; j < 8; ++j) o0[j] = f2bf(ts[c * 16 + j][e]);
#pragma unroll
    for (int j = 0; j < 8; ++j) o1[j] = f2bf(ts[c * 16 + 8 + j][e]);
    *reinterpret_cast<u16x8*>(&VtL[e][c * 16])     = o0;
    *reinterpret_cast<u16x8*>(&VtL[e][c * 16 + 8]) = o1;
  }
  __syncthreads();

  f32x4 acc[4] = {};
#pragma unroll
  for (int kk = 0; kk < 2; ++kk) {
    bf16x8 av = *reinterpret_cast<const bf16x8*>(&VtL[wave * 16 + l15][kk * 32 + l4 * 8]);
#pragma unroll
    for (int ni = 0; ni < 4; ++ni) {
      bf16x8 bk = *reinterpret_cast<const bf16x8*>(&KtL[ni * 16 + l15][kk * 32 + l4 * 8]);
      acc[ni] = __builtin_amdgcn_mfma_f32_16x16x32_bf16(av, bk, acc[ni], 0, 0, 0);
    }
  }
  u16* cb = ctxb + obase;
#pragma unroll
  for (int ni = 0; ni < 4; ++ni)
#pragma unroll
    for (int i = 0; i < 4; ++i)
      cb[(wave * 16 + l4 * 4 + i) * 64 + ni * 16 + l15] = f2bf(acc[ni][i]);
}

// -------------------- in-place exclusive cumsum over u ----------------------
__global__ __launch_bounds__(256) void scanctx(
    u16* __restrict__ ctxb, float* __restrict__ ksum) {
  const int bh = blockIdx.x >> 2, c = blockIdx.x & 3;
  const int tid = threadIdx.x;
  u16* p = ctxb + (size_t)bh * 64 * 4096 + c * 1024 + tid * 4;
  float* kp = ksum + (size_t)bh * 64 * 64 + tid;
  const bool dok = (c == 0) && (tid < 64);

  float r0 = 0.f, r1 = 0.f, r2 = 0.f, r3 = 0.f, runk = 0.f;
#define LC(i) (*reinterpret_cast<const u16x4*>(p + (size_t)(i) * 4096))
#define LK(i) (dok ? kp[(size_t)(i) * 64] : 0.f)
  u16x4 c0 = LC(0), c1 = LC(1), c2 = LC(2), c3 = LC(3);
  float k0 = LK(0), k1 = LK(1), k2 = LK(2), k3 = LK(3);
  for (int u = 0; u < 64; u += 4) {
    const int i4 = u + 4 < 64 ? u + 4 : 63, i5 = u + 5 < 64 ? u + 5 : 63;
    const int i6 = u + 6 < 64 ? u + 6 : 63, i7 = u + 7 < 64 ? u + 7 : 63;
    u16x4 n0 = LC(i4), n1 = LC(i5), n2 = LC(i6), n3 = LC(i7);
    float m0 = LK(i4), m1 = LK(i5), m2 = LK(i6), m3 = LK(i7);
#define STEP(idx, cv, kv)                                                  \
    {                                                                      \
      u16x4 o;                                                             \
      o.x = f2bf(r0); o.y = f2bf(r1); o.z = f2bf(r2); o.w = f2bf(r3);      \
      *reinterpret_cast<u16x4*>(p + (size_t)(idx) * 4096) = o;             \
      if (dok) kp[(size_t)(idx) * 64] = runk;                              \
      r0 += bf2f(cv.x); r1 += bf2f(cv.y); r2 += bf2f(cv.z);                \
      r3 += bf2f(cv.w); runk += kv;                                        \
    }
    STEP(u, c0, k0) STEP(u + 1, c1, k1) STEP(u + 2, c2, k2) STEP(u + 3, c3, k3)
#undef STEP
    c0 = n0; c1 = n1; c2 = n2; c3 = n3;
    k0 = m0; k1 = m1; k2 = m2; k3 = m3;
  }
#undef LC
#undef LK
}

// ---------------- apply: attn = (q @ ctx_excl) * Dinv -> AT -----------------
__global__ __launch_bounds__(256) void apply(
    const u16* __restrict__ Q, const u16* __restrict__ ctxc,
    const float* __restrict__ kcum, u16* __restrict__ AT) {
  const int bid = blockIdx.x;
  const int u = bid & 63, bh = bid >> 6, b = bh >> 4, h = bh & 15;
  const int tid = threadIdx.x, lane = tid & 63, wave = tid >> 6;
  const int l15 = lane & 15, l4 = lane >> 4;
  __shared__ float kc[64];
  __shared__ float dp[64][4];
  __shared__ float dinv[64];

  const size_t base = (size_t)bid * 4096;
  const u16* Qu = Q + base;
  if (tid < 64) kc[tid] = kcum[(size_t)bid * 64 + tid];
  __syncthreads();
  {
    int n = tid & 63, q = tid >> 6;
    const u16* qp = Qu + n * 64 + q * 16;
    float a = 0.f;
#pragma unroll
    for (int j = 0; j < 16; ++j) a += bf2f(qp[j]) * kc[q * 16 + j];
    dp[n][q] = a;
  }
  __syncthreads();
  if (tid < 64)
    dinv[tid] = 1.f / fmaxf(dp[tid][0] + dp[tid][1] + dp[tid][2] + dp[tid][3], 1e-3f);
  __syncthreads();

  f32x4 acc[4] = {};
  const u16* Cu = ctxc + base;
#pragma unroll
  for (int kk = 0; kk < 2; ++kk) {
    bf16x8 aq = *reinterpret_cast<const bf16x8*>(Qu + (wave * 16 + l15) * 64 + kk * 32 + l4 * 8);
#pragma unroll
    for (int ni = 0; ni < 4; ++ni) {
      bf16x8 bc = *reinterpret_cast<const bf16x8*>(Cu + (ni * 16 + l15) * 64 + kk * 32 + l4 * 8);
      acc[ni] = __builtin_amdgcn_mfma_f32_16x16x32_bf16(aq, bc, acc[ni], 0, 0, 0);
    }
  }
  const size_t orow = ((size_t)b * 4096 + u * 64 + wave * 16 + l4 * 4) * 1024 + h * 64;
#pragma unroll
  for (int i = 0; i < 4; ++i) {
    float di = dinv[wave * 16 + l4 * 4 + i];
#pragma unroll
    for (int ni = 0; ni < 4; ++ni)
      AT[orow + (size_t)i * 1024 + ni * 16 + l15] = f2bf(acc[ni][i] * di);
  }
}

// ----------------------------------------------------------------------------
extern "C" void kernel_launch(void* const* d_in, const int* in_sizes, int n_in,
                              void* d_out, int out_size, void* d_ws, size_t ws_size,
                              hipStream_t stream) {
  (void)in_sizes; (void)n_in; (void)out_size; (void)ws_size;
  const float* x      = (const float*)d_in[0];
  const float* qkv_w  = (const float*)d_in[1];
  const float* proj_w = (const float*)d_in[2];
  const float* proj_b = (const float*)d_in[3];
  float* out = (float*)d_out;

  char* ws = (char*)d_ws;
  u16* xb    = (u16*)(ws);
  u16* wq    = (u16*)(ws + 33554432);
  u16* wp    = (u16*)(ws + 39845888);
  u16* qkv   = (u16*)(ws + 41943040);
  u16* Qf    = (u16*)(ws + 142606336);
  u16* ctxb  = (u16*)(ws + 176160768);
  float* ksum = (float*)(ws + 209715200);
  u16* AT    = qkv;  // qkv region is dead after featuremap_ctx

  cvt_all<<<dim3(20480), dim3(256), 0, stream>>>(x, qkv_w, proj_w, xb, wq, wp);

  gemm256<true ><<<dim3(64 * 12), dim3(512), 0, stream>>>(xb, wq, nullptr, qkv,
                                                          3072, 1024, 16);
  featuremap_ctx<<<dim3(4096), dim3(256), 0, stream>>>(qkv, Qf, ctxb, ksum);
  scanctx<<<dim3(256), dim3(256), 0, stream>>>(ctxb, ksum);
  apply<<<dim3(4096), dim3(256), 0, stream>>>(Qf, ctxb, ksum, AT);
  gemm256<false><<<dim3(64 * 4), dim3(512), 0, stream>>>(AT, wp, proj_b, out,
                                                         1024, 1024, 16);
}

// Round 7
// 244.900 us; speedup vs baseline: 1.2176x; 1.1504x over previous
//
#include <hip/hip_runtime.h>
#include <stdint.h>

// ---------------------------------------------------------------------------
// Bucketed linear attention, round 6:
//   - GEMM K-loop reverted to R3's exact schedule (best measured: 42% MfmaUtil)
//   - feature maps (softmax(q), exp(k)) fused into QKV-GEMM epilogue, which
//     writes Qf/Kr/Vr directly in bucketed [bkt][n][64] layout; featuremap
//     kernel shrinks to buildctx (K^T V + ksum per bucket).
//   ws layout (~177 MB):
//     xb   bf16 x             33,554,432 B @ 0
//     wq   bf16 qkv_w          6,291,456 B @ 33554432
//     wp   bf16 proj_w         2,097,152 B @ 39845888
//     Qf   bf16 [bkt][n][e]   33,554,432 B @ 41943040
//     Kr   bf16 [bkt][n][d]   33,554,432 B @ 75497472   (exp'd; AT reuses this)
//     Vr   bf16 [bkt][n][e]   33,554,432 B @ 109051904
//     ctxb bf16 [bkt][e][d]   33,554,432 B @ 142606336  (in-place excl scan)
//     ksum f32  [bkt][d]       1,048,576 B @ 176160768  (in-place excl scan)
// ---------------------------------------------------------------------------

typedef unsigned short u16;
typedef unsigned int u32;
typedef u16   u16x4  __attribute__((ext_vector_type(4)));
typedef u16   u16x8  __attribute__((ext_vector_type(8)));
typedef float f32x4  __attribute__((ext_vector_type(4)));
typedef float float4v __attribute__((ext_vector_type(4)));
typedef __bf16 bf16x8 __attribute__((ext_vector_type(8)));

__device__ __forceinline__ u16 f2bf(float f) {
  return __builtin_bit_cast(u16, (__bf16)f);
}
__device__ __forceinline__ float bf2f(u16 h) {
  return (float)__builtin_bit_cast(__bf16, h);
}

__device__ __forceinline__ void stage16(const u16* g, u16* l) {
  __builtin_amdgcn_global_load_lds(
      (const __attribute__((address_space(1))) u32*)g,
      (__attribute__((address_space(3))) u32*)l, 16, 0, 0);
}

// ------------------- fp32 -> bf16 convert (all 3 inputs) --------------------
// ranges (u16x4 units): x 4194304 | qkv_w 786432 | proj_w 262144
__global__ __launch_bounds__(256) void cvt_all(
    const float* __restrict__ x, const float* __restrict__ wqf,
    const float* __restrict__ wpf, u16* __restrict__ xb,
    u16* __restrict__ wq, u16* __restrict__ wp) {
  int i = blockIdx.x * 256 + threadIdx.x;
  const float* in; u16* out; int j;
  if (i < 4194304)      { in = x;   out = xb; j = i; }
  else if (i < 4980736) { in = wqf; out = wq; j = i - 4194304; }
  else                  { in = wpf; out = wp; j = i - 4980736; }
  float4v v = reinterpret_cast<const float4v*>(in)[j];
  u16x4 o;
  o.x = f2bf(v.x); o.y = f2bf(v.y); o.z = f2bf(v.z); o.w = f2bf(v.w);
  reinterpret_cast<u16x4*>(out)[j] = o;
}

// ------------------ 256x256 NT bf16 MFMA GEMM (R3 schedule) -----------------
// C[M][N] = A[M][K] @ B[N][K]^T. BK=64, 8 waves (2Mx4N), wave out 128x64,
// 16x16x32 MFMA. LDS [2 dbuf][2 khalf][256][32] u16 per operand.
// Swizzle: phys 16B slot = logical ^ ((row>>1)&3) on global SOURCE of
// global_load_lds (LDS dest linear) and on ds_read (measured 0 conflicts).
// Per k-half: 12 ds_reads up front; STG interleaved; vmcnt(4)+barrier gate.
// EPI=0: float C + bias (proj). EPI=2: fused feature maps ->
//   bn 0-3: softmax_e(q)*e^-0.5 -> Qf[bkt][n][e]
//   bn 4-7: exp(k)             -> Kr[bkt][n][d]
//   bn 8-11: v                 -> Vr[bkt][n][e]
template <int EPI>
__global__ __launch_bounds__(512, 2) void gemm256(
    const u16* __restrict__ A,      // [M][K] bf16
    const u16* __restrict__ B,      // [N][K] bf16
    const float* __restrict__ bias, // [N] (EPI==0)
    float* __restrict__ Cf,         // (EPI==0)
    u16* __restrict__ Qf, u16* __restrict__ Kr, u16* __restrict__ Vr,
    int N, int K, int NT) {         // NT = K/64
  __shared__ u16 As[2][2][256][32];
  __shared__ u16 Bs[2][2][256][32];
  const int tid = threadIdx.x, lane = tid & 63, wave = tid >> 6;
  const int wm = wave >> 2, wn = wave & 3;
  const int l15 = lane & 15, l4 = lane >> 4;
  const int ntn = N >> 8;
  const int cpx = gridDim.x >> 3;
  const int bid = (blockIdx.x & 7) * cpx + (blockIdx.x >> 3);
  const int bm = bid / ntn, bn = bid % ntn;

  // staging: thread covers 16B at row (j*128 + tid>>2), phys slot tid&3;
  // fetch logical slot (tid&3)^((tid>>3)&3) so LDS dest stays linear.
  const int srow = tid >> 2;
  const int gsl8 = ((tid & 3) ^ ((tid >> 3) & 3)) * 8;
  const u16* Ag = A + (size_t)(bm * 256 + srow) * K + gsl8;
  const u16* Bg = B + (size_t)(bn * 256 + srow) * K + gsl8;
  const size_t rj = (size_t)128 * K;

  // ds_read: physical slot = l4 ^ ((row>>1)&3); row = base16 + l15.
  const int slotr = (l4 ^ ((l15 >> 1) & 3)) * 8;

  f32x4 acc[8][4] = {};
  bf16x8 a0, a1, a2, a3, a4, a5, a6, a7, b0, b1, b2, b3;

#define STG(P, buf, kh, kt)                                        \
  { const u16* g_ = P##g + (kt) + (kh) * 32;                       \
    stage16(g_,      &P##s[buf][kh][wave * 16][0]);                \
    stage16(g_ + rj, &P##s[buf][kh][128 + wave * 16][0]); }

#define LDA(r0_, r1_, r2_, r3_, kk, mh)                                  \
  { const u16* p_ = &As[cur][kk][wm * 128 + (mh) * 64 + l15][0] + slotr; \
    r0_ = *(const bf16x8*)(p_);                                          \
    r1_ = *(const bf16x8*)(p_ + 512);                                    \
    r2_ = *(const bf16x8*)(p_ + 1024);                                   \
    r3_ = *(const bf16x8*)(p_ + 1536); }

#define LDB(kk)                                                    \
  { const u16* p_ = &Bs[cur][kk][wn * 64 + l15][0] + slotr;        \
    b0 = *(const bf16x8*)(p_);                                     \
    b1 = *(const bf16x8*)(p_ + 512);                               \
    b2 = *(const bf16x8*)(p_ + 1024);                              \
    b3 = *(const bf16x8*)(p_ + 1536); }

#define MM(x, y, z) z = __builtin_amdgcn_mfma_f32_16x16x32_bf16(x, y, z, 0, 0, 0)
#define MFMA16(mb, x0, x1, x2, x3)                                 \
  __builtin_amdgcn_s_setprio(1);                                   \
  MM(x0, b0, acc[(mb) + 0][0]); MM(x0, b1, acc[(mb) + 0][1]);      \
  MM(x0, b2, acc[(mb) + 0][2]); MM(x0, b3, acc[(mb) + 0][3]);      \
  MM(x1, b0, acc[(mb) + 1][0]); MM(x1, b1, acc[(mb) + 1][1]);      \
  MM(x1, b2, acc[(mb) + 1][2]); MM(x1, b3, acc[(mb) + 1][3]);      \
  MM(x2, b0, acc[(mb) + 2][0]); MM(x2, b1, acc[(mb) + 2][1]);      \
  MM(x2, b2, acc[(mb) + 2][2]); MM(x2, b3, acc[(mb) + 2][3]);      \
  MM(x3, b0, acc[(mb) + 3][0]); MM(x3, b1, acc[(mb) + 3][1]);      \
  MM(x3, b2, acc[(mb) + 3][2]); MM(x3, b3, acc[(mb) + 3][3]);      \
  __builtin_amdgcn_s_setprio(0);

#define BARF()                                                     \
  { asm volatile("" ::: "memory");                                 \
    __builtin_amdgcn_s_barrier();                                  \
    asm volatile("" ::: "memory"); }

  // prologue: stage tile 0 fully into buf 0, drain, barrier.
  STG(A, 0, 0, 0) STG(B, 0, 0, 0) STG(A, 0, 1, 0) STG(B, 0, 1, 0)
  asm volatile("s_waitcnt vmcnt(0)" ::: "memory");
  __builtin_amdgcn_s_barrier();
  asm volatile("" ::: "memory");

  for (int t = 0; t < NT; ++t) {
    const int cur = t & 1, nxt = cur ^ 1;
    const int ktn = (t + 1) << 6;
    const bool pre = (t + 1 < NT);
    // ---- k-half 0: 12 ds_reads up front; second MFMA16 stall-free ----
    LDB(0)
    LDA(a0, a1, a2, a3, 0, 0)
    LDA(a4, a5, a6, a7, 0, 1)
    if (pre) STG(A, nxt, 0, ktn)
    MFMA16(0, a0, a1, a2, a3)
    if (pre) STG(B, nxt, 0, ktn)
    MFMA16(4, a4, a5, a6, a7)
    // gate: all waves' k1 staging (prev iter) landed -> k1 readable
    if (pre) { asm volatile("s_waitcnt vmcnt(4)" ::: "memory"); }
    else     { asm volatile("s_waitcnt vmcnt(0)" ::: "memory"); }
    BARF()
    // ---- k-half 1 ----
    LDB(1)
    LDA(a0, a1, a2, a3, 1, 0)
    LDA(a4, a5, a6, a7, 1, 1)
    if (pre) STG(A, nxt, 1, ktn)
    MFMA16(0, a0, a1, a2, a3)
    if (pre) STG(B, nxt, 1, ktn)
    MFMA16(4, a4, a5, a6, a7)
    // gate: all waves' k0 staging (this iter) landed -> next tile k0 ok
    if (pre) { asm volatile("s_waitcnt vmcnt(4)" ::: "memory"); }
    BARF()
  }
#undef STG
#undef LDA
#undef LDB
#undef MM
#undef MFMA16
#undef BARF

  // epilogue: D row=(lane>>4)*4+reg, col=lane&15
  const int row0 = bm * 256 + wm * 128 + l4 * 4;
  const int col0 = bn * 256 + wn * 64 + l15;
  if constexpr (EPI == 0) {
    float bv[4];
#pragma unroll
    for (int ni = 0; ni < 4; ++ni) bv[ni] = bias[col0 + ni * 16];
#pragma unroll
    for (int mi = 0; mi < 8; ++mi)
#pragma unroll
      for (int i = 0; i < 4; ++i) {
        size_t r = (size_t)(row0 + mi * 16 + i) * N;
#pragma unroll
        for (int ni = 0; ni < 4; ++ni)
          Cf[r + col0 + ni * 16] = acc[mi][ni][i] + bv[ni];
      }
  } else {
    // fused feature maps. i3 region & head are block/wave-uniform.
    const int i3 = bn >> 2;                  // 0=q, 1=k, 2=v
    const int h  = ((bn & 3) << 2) + wn;     // global head 0..15
    u16* dst = (i3 == 0) ? Qf : (i3 == 1 ? Kr : Vr);
#pragma unroll
    for (int mi = 0; mi < 8; ++mi)
#pragma unroll
      for (int i = 0; i < 4; ++i) {
        const int row = row0 + mi * 16 + i;
        const int bb = row >> 12, uu = (row >> 6) & 63, nn = row & 63;
        u16* op = dst + ((size_t)((bb * 16 + h) * 64 + uu)) * 4096
                      + nn * 64 + l15;
        float v0 = acc[mi][0][i], v1 = acc[mi][1][i];
        float v2 = acc[mi][2][i], v3 = acc[mi][3][i];
        if (i3 == 0) {
          // row softmax over e=64: 4 in-lane + 16-lane group (masks 1,2,4,8
          // toggle l15 bits only; l4 row-subgroup untouched)
          float mx = fmaxf(fmaxf(v0, v1), fmaxf(v2, v3));
          mx = fmaxf(mx, __shfl_xor(mx, 1));
          mx = fmaxf(mx, __shfl_xor(mx, 2));
          mx = fmaxf(mx, __shfl_xor(mx, 4));
          mx = fmaxf(mx, __shfl_xor(mx, 8));
          float e0 = __expf(v0 - mx), e1 = __expf(v1 - mx);
          float e2 = __expf(v2 - mx), e3 = __expf(v3 - mx);
          float s = e0 + e1 + e2 + e3;
          s += __shfl_xor(s, 1); s += __shfl_xor(s, 2);
          s += __shfl_xor(s, 4); s += __shfl_xor(s, 8);
          float inv = 0.125f / s;  // e^-0.5 = 1/8
          op[0]  = f2bf(e0 * inv); op[16] = f2bf(e1 * inv);
          op[32] = f2bf(e2 * inv); op[48] = f2bf(e3 * inv);
        } else if (i3 == 1) {
          op[0]  = f2bf(__expf(v0)); op[16] = f2bf(__expf(v1));
          op[32] = f2bf(__expf(v2)); op[48] = f2bf(__expf(v3));
        } else {
          op[0]  = f2bf(v0); op[16] = f2bf(v1);
          op[32] = f2bf(v2); op[48] = f2bf(v3);
        }
      }
  }
}

// ---------------- per-bucket K^T V + ksum (from Kr, Vr) ---------------------
// One block per bucket. Kr already exp'd. LDS-transpose then 16x16x32 MFMA.
__global__ __launch_bounds__(256) void buildctx(
    const u16* __restrict__ Kr,  // [bkt][n][d] bf16 (exp'd)
    const u16* __restrict__ Vr,  // [bkt][n][e] bf16
    u16* __restrict__ ctxb, float* __restrict__ ksum) {
  const int bid = blockIdx.x;
  const int tid = threadIdx.x, lane = tid & 63, wave = tid >> 6;
  const int l15 = lane & 15, l4 = lane >> 4;
  __shared__ float ts[64][65];
  __shared__ u16 KtL[64][72];
  __shared__ u16 VtL[64][72];
  __shared__ float dp[64][4];

  const size_t base = (size_t)bid * 4096;

  // K stage + transpose into KtL
  {
    int n = tid >> 2, c = tid & 3;
    const u16* kp = Kr + base + n * 64 + c * 16;
#pragma unroll
    for (int j = 0; j < 16; ++j) ts[n][c * 16 + j] = bf2f(kp[j]);
  }
  __syncthreads();
  {
    int d = tid >> 2, c = tid & 3;
    u16x8 o0, o1;
#pragma unroll
    for (int j = 0; j < 8; ++j) o0[j] = f2bf(ts[c * 16 + j][d]);
#pragma unroll
    for (int j = 0; j < 8; ++j) o1[j] = f2bf(ts[c * 16 + 8 + j][d]);
    *reinterpret_cast<u16x8*>(&KtL[d][c * 16])     = o0;
    *reinterpret_cast<u16x8*>(&KtL[d][c * 16 + 8]) = o1;
  }
  __syncthreads();
  // ksum partials; V stage into ts
  {
    int d = tid & 63, q = tid >> 6;
    float a = 0.f;
#pragma unroll
    for (int j = 0; j < 16; ++j) a += bf2f(KtL[d][q * 16 + j]);
    dp[d][q] = a;
  }
  {
    int n = tid >> 2, c = tid & 3;
    const u16* vp = Vr + base + n * 64 + c * 16;
#pragma unroll
    for (int j = 0; j < 16; ++j) ts[n][c * 16 + j] = bf2f(vp[j]);
  }
  __syncthreads();
  if (tid < 64)
    ksum[(size_t)bid * 64 + tid] = dp[tid][0] + dp[tid][1] + dp[tid][2] + dp[tid][3];
  {
    int e = tid >> 2, c = tid & 3;
    u16x8 o0, o1;
#pragma unroll
    for (int j = 0; j < 8; ++j) o0[j] = f2bf(ts[c * 16 + j][e]);
#pragma unroll
    for (int j = 0; j < 8; ++j) o1[j] = f2bf(ts[c * 16 + 8 + j][e]);
    *reinterpret_cast<u16x8*>(&VtL[e][c * 16])     = o0;
    *reinterpret_cast<u16x8*>(&VtL[e][c * 16 + 8]) = o1;
  }
  __syncthreads();

  // ctxT[e][d] = sum_n VtL[e][n] * KtL[d][n]; wave -> 16 e-rows
  f32x4 acc[4] = {};
#pragma unroll
  for (int kk = 0; kk < 2; ++kk) {
    bf16x8 av = *reinterpret_cast<const bf16x8*>(&VtL[wave * 16 + l15][kk * 32 + l4 * 8]);
#pragma unroll
    for (int ni = 0; ni < 4; ++ni) {
      bf16x8 bk = *reinterpret_cast<const bf16x8*>(&KtL[ni * 16 + l15][kk * 32 + l4 * 8]);
      acc[ni] = __builtin_amdgcn_mfma_f32_16x16x32_bf16(av, bk, acc[ni], 0, 0, 0);
    }
  }
  u16* cb = ctxb + base;
#pragma unroll
  for (int ni = 0; ni < 4; ++ni)
#pragma unroll
    for (int i = 0; i < 4; ++i)
      cb[(wave * 16 + l4 * 4 + i) * 64 + ni * 16 + l15] = f2bf(acc[ni][i]);
}

// -------------------- in-place exclusive cumsum over u ----------------------
__global__ __launch_bounds__(256) void scanctx(
    u16* __restrict__ ctxb, float* __restrict__ ksum) {
  const int bh = blockIdx.x >> 2, c = blockIdx.x & 3;
  const int tid = threadIdx.x;
  u16* p = ctxb + (size_t)bh * 64 * 4096 + c * 1024 + tid * 4;
  float* kp = ksum + (size_t)bh * 64 * 64 + tid;
  const bool dok = (c == 0) && (tid < 64);

  float r0 = 0.f, r1 = 0.f, r2 = 0.f, r3 = 0.f, runk = 0.f;
#define LC(i) (*reinterpret_cast<const u16x4*>(p + (size_t)(i) * 4096))
#define LK(i) (dok ? kp[(size_t)(i) * 64] : 0.f)
  u16x4 c0 = LC(0), c1 = LC(1), c2 = LC(2), c3 = LC(3);
  float k0 = LK(0), k1 = LK(1), k2 = LK(2), k3 = LK(3);
  for (int u = 0; u < 64; u += 4) {
    const int i4 = u + 4 < 64 ? u + 4 : 63, i5 = u + 5 < 64 ? u + 5 : 63;
    const int i6 = u + 6 < 64 ? u + 6 : 63, i7 = u + 7 < 64 ? u + 7 : 63;
    u16x4 n0 = LC(i4), n1 = LC(i5), n2 = LC(i6), n3 = LC(i7);
    float m0 = LK(i4), m1 = LK(i5), m2 = LK(i6), m3 = LK(i7);
#define STEP(idx, cv, kv)                                                  \
    {                                                                      \
      u16x4 o;                                                             \
      o.x = f2bf(r0); o.y = f2bf(r1); o.z = f2bf(r2); o.w = f2bf(r3);      \
      *reinterpret_cast<u16x4*>(p + (size_t)(idx) * 4096) = o;             \
      if (dok) kp[(size_t)(idx) * 64] = runk;                              \
      r0 += bf2f(cv.x); r1 += bf2f(cv.y); r2 += bf2f(cv.z);                \
      r3 += bf2f(cv.w); runk += kv;                                        \
    }
    STEP(u, c0, k0) STEP(u + 1, c1, k1) STEP(u + 2, c2, k2) STEP(u + 3, c3, k3)
#undef STEP
    c0 = n0; c1 = n1; c2 = n2; c3 = n3;
    k0 = m0; k1 = m1; k2 = m2; k3 = m3;
  }
#undef LC
#undef LK
}

// ---------------- apply: attn = (q @ ctx_excl) * Dinv -> AT -----------------
__global__ __launch_bounds__(256) void apply(
    const u16* __restrict__ Q, const u16* __restrict__ ctxc,
    const float* __restrict__ kcum, u16* __restrict__ AT) {
  const int bid = blockIdx.x;
  const int u = bid & 63, bh = bid >> 6, b = bh >> 4, h = bh & 15;
  const int tid = threadIdx.x, lane = tid & 63, wave = tid >> 6;
  const int l15 = lane & 15, l4 = lane >> 4;
  __shared__ float kc[64];
  __shared__ float dp[64][4];
  __shared__ float dinv[64];

  const size_t base = (size_t)bid * 4096;
  const u16* Qu = Q + base;
  if (tid < 64) kc[tid] = kcum[(size_t)bid * 64 + tid];
  __syncthreads();
  {
    int n = tid & 63, q = tid >> 6;
    const u16* qp = Qu + n * 64 + q * 16;
    float a = 0.f;
#pragma unroll
    for (int j = 0; j < 16; ++j) a += bf2f(qp[j]) * kc[q * 16 + j];
    dp[n][q] = a;
  }
  __syncthreads();
  if (tid < 64)
    dinv[tid] = 1.f / fmaxf(dp[tid][0] + dp[tid][1] + dp[tid][2] + dp[tid][3], 1e-3f);
  __syncthreads();

  f32x4 acc[4] = {};
  const u16* Cu = ctxc + base;
#pragma unroll
  for (int kk = 0; kk < 2; ++kk) {
    bf16x8 aq = *reinterpret_cast<const bf16x8*>(Qu + (wave * 16 + l15) * 64 + kk * 32 + l4 * 8);
#pragma unroll
    for (int ni = 0; ni < 4; ++ni) {
      bf16x8 bc = *reinterpret_cast<const bf16x8*>(Cu + (ni * 16 + l15) * 64 + kk * 32 + l4 * 8);
      acc[ni] = __builtin_amdgcn_mfma_f32_16x16x32_bf16(aq, bc, acc[ni], 0, 0, 0);
    }
  }
  const size_t orow = ((size_t)b * 4096 + u * 64 + wave * 16 + l4 * 4) * 1024 + h * 64;
#pragma unroll
  for (int i = 0; i < 4; ++i) {
    float di = dinv[wave * 16 + l4 * 4 + i];
#pragma unroll
    for (int ni = 0; ni < 4; ++ni)
      AT[orow + (size_t)i * 1024 + ni * 16 + l15] = f2bf(acc[ni][i] * di);
  }
}

// ----------------------------------------------------------------------------
extern "C" void kernel_launch(void* const* d_in, const int* in_sizes, int n_in,
                              void* d_out, int out_size, void* d_ws, size_t ws_size,
                              hipStream_t stream) {
  (void)in_sizes; (void)n_in; (void)out_size; (void)ws_size;
  const float* x      = (const float*)d_in[0];
  const float* qkv_w  = (const float*)d_in[1];
  const float* proj_w = (const float*)d_in[2];
  const float* proj_b = (const float*)d_in[3];
  float* out = (float*)d_out;

  char* ws = (char*)d_ws;
  u16* xb    = (u16*)(ws);
  u16* wq    = (u16*)(ws + 33554432);
  u16* wp    = (u16*)(ws + 39845888);
  u16* Qf    = (u16*)(ws + 41943040);
  u16* Kr    = (u16*)(ws + 75497472);
  u16* Vr    = (u16*)(ws + 109051904);
  u16* ctxb  = (u16*)(ws + 142606336);
  float* ksum = (float*)(ws + 176160768);
  u16* AT    = Kr;  // Kr is dead after buildctx; apply writes AT over it

  cvt_all<<<dim3(20480), dim3(256), 0, stream>>>(x, qkv_w, proj_w, xb, wq, wp);

  gemm256<2><<<dim3(64 * 12), dim3(512), 0, stream>>>(
      xb, wq, nullptr, nullptr, Qf, Kr, Vr, 3072, 1024, 16);
  buildctx<<<dim3(4096), dim3(256), 0, stream>>>(Kr, Vr, ctxb, ksum);
  scanctx<<<dim3(256), dim3(256), 0, stream>>>(ctxb, ksum);
  apply<<<dim3(4096), dim3(256), 0, stream>>>(Qf, ctxb, ksum, AT);
  gemm256<0><<<dim3(64 * 4), dim3(512), 0, stream>>>(
      AT, wp, proj_b, out, nullptr, nullptr, nullptr, 1024, 1024, 16);
}